// Round 9
// baseline (7201.080 us; speedup 1.0000x reference)
//
#include <hip/hip_runtime.h>
#include <math.h>

#define N_NODES 20000
#define N_EDGES 320000
#define F_IN 128
#define C 300
#define L_STEPS 8
#define KP 320                 // padded K (multiple of 32)
#define NPAD 304               // padded gate-col dim (19*16)
#define GOFS 97280             // 40*NPAD*8, per-gate block in swizzled weights
#define WSTEP 291840           // 3*GOFS, per (layer,step)
#define LOSCALE 2048.0f        // lo-part pre-scale (2^11), avoids fp16 denormals

typedef _Float16 half8 __attribute__((ext_vector_type(8)));
typedef _Float16 half4 __attribute__((ext_vector_type(4)));
typedef __attribute__((ext_vector_type(4))) float floatx4;

__device__ __forceinline__ void split16(float x, _Float16& hi, _Float16& lo) {
    hi = (_Float16)x;
    lo = (_Float16)((x - (float)hi) * LOSCALE);
}

// ---------------- pad x -> h (fp32) + hh/hl (fp16 split, stride KP) --------
__global__ void pad_kernel(const float* __restrict__ x, float* __restrict__ h,
                           _Float16* __restrict__ hh, _Float16* __restrict__ hl) {
    int idx = blockIdx.x * blockDim.x + threadIdx.x;
    if (idx >= N_NODES * KP) return;
    int n = idx / KP, c = idx - n * KP;
    float v = (c < F_IN) ? x[n * F_IN + c] : 0.0f;
    if (c < C) h[(size_t)n * C + c] = v;
    _Float16 hi, lo; split16(v, hi, lo);
    hh[idx] = hi; hl[idx] = lo;
}

// ---------------- CSR build (verified round 4) ----------------
__global__ void hist_kernel(const int* __restrict__ dst, int* __restrict__ deg) {
    int e = blockIdx.x * blockDim.x + threadIdx.x;
    if (e < N_EDGES) atomicAdd(&deg[dst[e]], 1);
}

__global__ void scan_kernel(const int* __restrict__ deg, int* __restrict__ row_ptr) {
    __shared__ int part[1024];
    const int PER = 20;
    int t = threadIdx.x;
    int base = t * PER;
    int vals[PER];
    int s = 0;
    #pragma unroll
    for (int i = 0; i < PER; ++i) {
        int idx = base + i;
        int v = (idx < N_NODES) ? deg[idx] : 0;
        vals[i] = s; s += v;
    }
    part[t] = s;
    __syncthreads();
    for (int off = 1; off < 1024; off <<= 1) {
        int v = (t >= off) ? part[t - off] : 0;
        __syncthreads();
        part[t] += v;
        __syncthreads();
    }
    int pre = (t == 0) ? 0 : part[t - 1];
    #pragma unroll
    for (int i = 0; i < PER; ++i) {
        int idx = base + i;
        if (idx < N_NODES) row_ptr[idx] = pre + vals[i];
    }
    if (t == 0) row_ptr[N_NODES] = N_EDGES;
}

__global__ void cursor_copy(const int* __restrict__ row_ptr, int* __restrict__ cur) {
    int i = blockIdx.x * blockDim.x + threadIdx.x;
    if (i < N_NODES) cur[i] = row_ptr[i];
}

__global__ void fill_kernel(const int* __restrict__ src, const int* __restrict__ dst,
                            int* __restrict__ cur, int* __restrict__ colx) {
    int e = blockIdx.x * blockDim.x + threadIdx.x;
    if (e >= N_EDGES) return;
    int d = dst[e];
    int p = atomicAdd(&cur[d], 1);
    colx[p] = src[e];
}

// ---- WcombT[r][gn] = sum_c W[r][c]*wih[gn][c]; swizzled fp16 hi/lo --------
__launch_bounds__(256)
__global__ void wcomb_split(const float* __restrict__ W1, const float* __restrict__ W2,
                            const float* __restrict__ wih1, const float* __restrict__ wih2,
                            _Float16* __restrict__ whi, _Float16* __restrict__ wlo) {
    int z = blockIdx.z, layer = z >> 3, step = z & 7;
    const float* A  = (layer ? W2 : W1) + (size_t)step * C * C;  // [r][c]
    const float* Bm = layer ? wih2 : wih1;                       // [gn][c]
    _Float16* ohi = whi + (size_t)z * WSTEP;
    _Float16* olo = wlo + (size_t)z * WSTEP;
    __shared__ float As[16][68];
    __shared__ float Bs[16][68];
    int tid = threadIdx.x;
    int tx = tid & 15, ty = tid >> 4;
    int rowBase = blockIdx.y * 64, colBase = blockIdx.x * 64;
    float acc[4][4] = {};
    int lr = tid >> 2, k4 = (tid & 3) * 4;
    for (int k0 = 0; k0 < C; k0 += 16) {
        {
            int gr = rowBase + lr;
            int gn = colBase + lr;
            #pragma unroll
            for (int j = 0; j < 4; ++j) {
                int k = k0 + k4 + j;
                As[k4 + j][lr] = (gr < C && k < C) ? A[(size_t)gr * C + k] : 0.f;
                Bs[k4 + j][lr] = (gn < 3 * C && k < C) ? Bm[(size_t)gn * C + k] : 0.f;
            }
        }
        __syncthreads();
        #pragma unroll
        for (int k = 0; k < 16; ++k) {
            float4 a = *(const float4*)&As[k][ty * 4];
            float4 b = *(const float4*)&Bs[k][tx * 4];
            float av[4] = {a.x, a.y, a.z, a.w};
            float bv[4] = {b.x, b.y, b.z, b.w};
            #pragma unroll
            for (int i = 0; i < 4; ++i)
                #pragma unroll
                for (int j = 0; j < 4; ++j)
                    acc[i][j] += av[i] * bv[j];
        }
        __syncthreads();
    }
    #pragma unroll
    for (int i = 0; i < 4; ++i) {
        int r = rowBase + ty * 4 + i;
        if (r >= C) continue;
        #pragma unroll
        for (int j = 0; j < 4; ++j) {
            int gn = colBase + tx * 4 + j;
            if (gn >= 3 * C) continue;
            int g = (gn >= 2 * C) ? 2 : ((gn >= C) ? 1 : 0);
            int n = gn - g * C;
            size_t idx = (((size_t)g * 40 + (r >> 3)) * NPAD + n) * 8 + (r & 7);
            _Float16 hi, lo; split16(acc[i][j], hi, lo);
            ohi[idx] = hi; olo[idx] = lo;
        }
    }
}

// ---- whh^T swizzle + split: B[k][gn] = whh[gn][k], fp16 hi/lo ----
__global__ void whh_split(const float* __restrict__ whh1, const float* __restrict__ whh2,
                          _Float16* __restrict__ whi, _Float16* __restrict__ wlo) {
    int idx = blockIdx.x * blockDim.x + threadIdx.x;
    if (idx >= 2 * 3 * C * C) return;
    int k = idx % C;
    int rest = idx / C;
    int gn = rest % (3 * C);
    int layer = rest / (3 * C);
    int g = (gn >= 2 * C) ? 2 : ((gn >= C) ? 1 : 0);
    int n = gn - g * C;
    float v = (layer ? whh2 : whh1)[(size_t)gn * C + k];
    size_t o = (size_t)layer * WSTEP + (((size_t)g * 40 + (k >> 3)) * NPAD + n) * 8 + (k & 7);
    _Float16 hi, lo; split16(v, hi, lo);
    whi[o] = hi; wlo[o] = lo;
}

// ---- CSR gather from fp32 h -> exact fp16 hi/lo split agg [N x KP] ----
__global__ void aggregate_kernel(const float* __restrict__ h,
                                 const int* __restrict__ rowp,
                                 const int* __restrict__ colx,
                                 _Float16* __restrict__ agh, _Float16* __restrict__ agl) {
    const int node = blockIdx.x * 4 + (threadIdx.x >> 6);
    const int lane = threadIdx.x & 63;
    const int beg = rowp[node], end = rowp[node + 1];
    float4 a0 = make_float4(0.f, 0.f, 0.f, 0.f);
    float4 a1 = make_float4(0.f, 0.f, 0.f, 0.f);
    const bool tail = lane < 11;       // chunks 64..74 cover cols 256..299
    for (int e = beg; e < end; ++e) {
        const float* row = h + (size_t)colx[e] * C;
        float4 v = *(const float4*)&row[lane * 4];
        a0.x += v.x; a0.y += v.y; a0.z += v.z; a0.w += v.w;
        if (tail) {
            float4 u = *(const float4*)&row[(64 + lane) * 4];
            a1.x += u.x; a1.y += u.y; a1.z += u.z; a1.w += u.w;
        }
    }
    half4 vh, vl;
    {
        _Float16 hi, lo;
        split16(a0.x, hi, lo); vh[0] = hi; vl[0] = lo;
        split16(a0.y, hi, lo); vh[1] = hi; vl[1] = lo;
        split16(a0.z, hi, lo); vh[2] = hi; vl[2] = lo;
        split16(a0.w, hi, lo); vh[3] = hi; vl[3] = lo;
    }
    _Float16* oh = agh + (size_t)node * KP;
    _Float16* ol = agl + (size_t)node * KP;
    *(half4*)&oh[lane * 4] = vh;
    *(half4*)&ol[lane * 4] = vl;
    if (tail) {
        _Float16 hi, lo;
        split16(a1.x, hi, lo); vh[0] = hi; vl[0] = lo;
        split16(a1.y, hi, lo); vh[1] = hi; vl[1] = lo;
        split16(a1.z, hi, lo); vh[2] = hi; vl[2] = lo;
        split16(a1.w, hi, lo); vh[3] = hi; vl[3] = lo;
        *(half4*)&oh[(64 + lane) * 4] = vh;
        *(half4*)&ol[(64 + lane) * 4] = vl;
    }
}

// ---- B-fragment bundle (12 matrices: {wc,wh} x {r,z,n} x {hi,lo}) ----
struct BFrag { half8 v[12]; };
__device__ __forceinline__ BFrag load_bfrags(const _Float16* __restrict__ wch,
                                             const _Float16* __restrict__ wcl,
                                             const _Float16* __restrict__ whh_,
                                             const _Float16* __restrict__ whl_,
                                             int kc, int ncol) {
    BFrag f;
    const size_t bofs = ((size_t)kc * NPAD + ncol) * 8;
    f.v[0]  = *(const half8*)&wch[bofs];
    f.v[1]  = *(const half8*)&wch[GOFS + bofs];
    f.v[2]  = *(const half8*)&wch[2 * GOFS + bofs];
    f.v[3]  = *(const half8*)&wcl[bofs];
    f.v[4]  = *(const half8*)&wcl[GOFS + bofs];
    f.v[5]  = *(const half8*)&wcl[2 * GOFS + bofs];
    f.v[6]  = *(const half8*)&whh_[bofs];
    f.v[7]  = *(const half8*)&whh_[GOFS + bofs];
    f.v[8]  = *(const half8*)&whh_[2 * GOFS + bofs];
    f.v[9]  = *(const half8*)&whl_[bofs];
    f.v[10] = *(const half8*)&whl_[GOFS + bofs];
    f.v[11] = *(const half8*)&whl_[2 * GOFS + bofs];
    return f;
}

// ---- fused MFMA GRU step, fp16 hi/lo split arithmetic ----
// No LDS; state DOUBLE-BUFFERED (read hh_in/hl_in, write hh_out/hl_out)
// to avoid the in-place read/write race that broke round 8.
__launch_bounds__(256, 4)
__global__ void gru_f16(const _Float16* __restrict__ hh_in, const _Float16* __restrict__ hl_in,
                        _Float16* __restrict__ hh_out, _Float16* __restrict__ hl_out,
                        const _Float16* __restrict__ agh, const _Float16* __restrict__ agl,
                        const _Float16* __restrict__ wch, const _Float16* __restrict__ wcl,
                        const _Float16* __restrict__ whh_, const _Float16* __restrict__ whl_,
                        const float* __restrict__ bih, const float* __restrict__ bhh,
                        float* __restrict__ h) {
    const int tid = threadIdx.x;
    const int rowBase = blockIdx.x * 32;    // 625 * 32 = 20000 exact
    const int lane = tid & 63, w = tid >> 6;
    const int quad = lane >> 4, n15 = lane & 15;
    const int s = w >> 1;          // row-subtile (0 or 1)
    const int parity = w & 1;      // ct parity
    const int arow = s * 16 + n15; // A-fragment row within block
    const size_t rofs = (size_t)(rowBase + arow) * KP;
    const _Float16* phh = hh_in + rofs;
    const _Float16* phl = hl_in + rofs;
    const _Float16* pgh = agh + rofs;
    const _Float16* pgl = agl + rofs;

    for (int ct = parity; ct < 19; ct += 2) {
        floatx4 a1[6], a2[6];
        #pragma unroll
        for (int g = 0; g < 6; ++g) {
            a1[g] = (floatx4){0.f, 0.f, 0.f, 0.f};
            a2[g] = (floatx4){0.f, 0.f, 0.f, 0.f};
        }
        const int ncol = ct * 16 + n15;   // 0..303
        BFrag B0 = load_bfrags(wch, wcl, whh_, whl_, 0 * 4 + quad, ncol);
        BFrag B1;
        #pragma unroll
        for (int kt = 0; kt < 10; ++kt) {
            if (kt < 9) {
                if (kt & 1) B0 = load_bfrags(wch, wcl, whh_, whl_, (kt + 1) * 4 + quad, ncol);
                else        B1 = load_bfrags(wch, wcl, whh_, whl_, (kt + 1) * 4 + quad, ncol);
            }
            const BFrag& B = (kt & 1) ? B1 : B0;
            const int ko = kt * 32 + quad * 8;
            half8 GH = *(const half8*)&pgh[ko];
            half8 AH = *(const half8*)&phh[ko];
            half8 AL = *(const half8*)&phl[ko];
            half8 GL = *(const half8*)&pgl[ko];
            a1[0] = __builtin_amdgcn_mfma_f32_16x16x32_f16(GH, B.v[0], a1[0], 0, 0, 0);
            a2[0] = __builtin_amdgcn_mfma_f32_16x16x32_f16(GH, B.v[3], a2[0], 0, 0, 0);
            a2[0] = __builtin_amdgcn_mfma_f32_16x16x32_f16(GL, B.v[0], a2[0], 0, 0, 0);
            a1[1] = __builtin_amdgcn_mfma_f32_16x16x32_f16(GH, B.v[1], a1[1], 0, 0, 0);
            a2[1] = __builtin_amdgcn_mfma_f32_16x16x32_f16(GH, B.v[4], a2[1], 0, 0, 0);
            a2[1] = __builtin_amdgcn_mfma_f32_16x16x32_f16(GL, B.v[1], a2[1], 0, 0, 0);
            a1[2] = __builtin_amdgcn_mfma_f32_16x16x32_f16(GH, B.v[2], a1[2], 0, 0, 0);
            a2[2] = __builtin_amdgcn_mfma_f32_16x16x32_f16(GH, B.v[5], a2[2], 0, 0, 0);
            a2[2] = __builtin_amdgcn_mfma_f32_16x16x32_f16(GL, B.v[2], a2[2], 0, 0, 0);
            a1[3] = __builtin_amdgcn_mfma_f32_16x16x32_f16(AH, B.v[6], a1[3], 0, 0, 0);
            a2[3] = __builtin_amdgcn_mfma_f32_16x16x32_f16(AH, B.v[9], a2[3], 0, 0, 0);
            a2[3] = __builtin_amdgcn_mfma_f32_16x16x32_f16(AL, B.v[6], a2[3], 0, 0, 0);
            a1[4] = __builtin_amdgcn_mfma_f32_16x16x32_f16(AH, B.v[7], a1[4], 0, 0, 0);
            a2[4] = __builtin_amdgcn_mfma_f32_16x16x32_f16(AH, B.v[10], a2[4], 0, 0, 0);
            a2[4] = __builtin_amdgcn_mfma_f32_16x16x32_f16(AL, B.v[7], a2[4], 0, 0, 0);
            a1[5] = __builtin_amdgcn_mfma_f32_16x16x32_f16(AH, B.v[8], a1[5], 0, 0, 0);
            a2[5] = __builtin_amdgcn_mfma_f32_16x16x32_f16(AH, B.v[11], a2[5], 0, 0, 0);
            a2[5] = __builtin_amdgcn_mfma_f32_16x16x32_f16(AL, B.v[8], a2[5], 0, 0, 0);
        }
        const int col = ncol;
        if (col < C) {
            const float invS = 1.0f / LOSCALE;
            float br = bih[col], bz = bih[C + col], bn = bih[2 * C + col];
            float cr = bhh[col], cz = bhh[C + col], cn = bhh[2 * C + col];
            #pragma unroll
            for (int i = 0; i < 4; ++i) {
                int grow = rowBase + s * 16 + quad * 4 + i;
                float ir  = a1[0][i] + a2[0][i] * invS + br;
                float iz  = a1[1][i] + a2[1][i] * invS + bz;
                float inn = a1[2][i] + a2[2][i] * invS + bn;
                float hr  = a1[3][i] + a2[3][i] * invS + cr;
                float hz  = a1[4][i] + a2[4][i] * invS + cz;
                float hn  = a1[5][i] + a2[5][i] * invS + cn;
                float r = 1.f / (1.f + __expf(-(ir + hr)));
                float z = 1.f / (1.f + __expf(-(iz + hz)));
                float nn = tanhf(inn + r * hn);
                float hold = h[(size_t)grow * C + col];
                float hnew = (1.f - z) * nn + z * hold;
                h[(size_t)grow * C + col] = hnew;
                _Float16 nh, nl; split16(hnew, nh, nl);
                hh_out[(size_t)grow * KP + col] = nh;
                hl_out[(size_t)grow * KP + col] = nl;
            }
        }
    }
}

// ---------------- relu (h fp32 + hh/hl fp16) ----------------
__global__ void relu_kernel(float* __restrict__ h, _Float16* __restrict__ hh,
                            _Float16* __restrict__ hl) {
    int idx = blockIdx.x * blockDim.x + threadIdx.x;
    if (idx >= N_NODES * C) return;
    int n = idx / C, c = idx - n * C;
    float v = fmaxf(h[idx], 0.f);
    h[idx] = v;
    _Float16 hi, lo; split16(v, hi, lo);
    hh[(size_t)n * KP + c] = hi;
    hl[(size_t)n * KP + c] = lo;
}

// ---------------- mean pool ----------------
__global__ void pool_kernel(const float* __restrict__ h, float* __restrict__ pooled) {
    int c = threadIdx.x;
    if (c >= C) return;
    float acc = 0.f;
    for (int n = blockIdx.x; n < N_NODES; n += gridDim.x)
        acc += h[(size_t)n * C + c];
    atomicAdd(&pooled[c], acc);
}

// ---------------- log_softmax ----------------
__global__ void lsm_kernel(const float* __restrict__ pooled, float* __restrict__ out) {
    __shared__ float sm[512];
    int t = threadIdx.x;
    float v = (t < C) ? pooled[t] * (1.0f / N_NODES) : -INFINITY;
    sm[t] = v;
    __syncthreads();
    for (int s = 256; s > 0; s >>= 1) {
        if (t < s) sm[t] = fmaxf(sm[t], sm[t + s]);
        __syncthreads();
    }
    float mx = sm[0];
    __syncthreads();
    float e = (t < C) ? expf(v - mx) : 0.f;
    sm[t] = e;
    __syncthreads();
    for (int s = 256; s > 0; s >>= 1) {
        if (t < s) sm[t] += sm[t + s];
        __syncthreads();
    }
    float lse = logf(sm[0]);
    if (t < C) out[t] = (v - mx) - lse;
}

extern "C" void kernel_launch(void* const* d_in, const int* in_sizes, int n_in,
                              void* d_out, int out_size, void* d_ws, size_t ws_size,
                              hipStream_t stream) {
    const float* x      = (const float*)d_in[0];
    const int*   ei     = (const int*)d_in[1];
    const int*   src    = ei;
    const int*   dst    = ei + N_EDGES;
    const float* W1     = (const float*)d_in[2];
    const float* g1_wih = (const float*)d_in[3];
    const float* g1_whh = (const float*)d_in[4];
    const float* g1_bih = (const float*)d_in[5];
    const float* g1_bhh = (const float*)d_in[6];
    const float* W2     = (const float*)d_in[7];
    const float* g2_wih = (const float*)d_in[8];
    const float* g2_whh = (const float*)d_in[9];
    const float* g2_bih = (const float*)d_in[10];
    const float* g2_bhh = (const float*)d_in[11];

    char* p = (char*)d_ws;
    float* h = (float*)p;               p += (size_t)N_NODES * C * 4;    // 24.0 MB
    _Float16* hh0 = (_Float16*)p;       p += (size_t)N_NODES * KP * 2;   // 12.8 MB
    _Float16* hl0 = (_Float16*)p;       p += (size_t)N_NODES * KP * 2;   // 12.8 MB
    _Float16* hh1 = (_Float16*)p;       p += (size_t)N_NODES * KP * 2;   // 12.8 MB
    _Float16* hl1 = (_Float16*)p;       p += (size_t)N_NODES * KP * 2;   // 12.8 MB
    _Float16* agh = (_Float16*)p;       p += (size_t)N_NODES * KP * 2;   // 12.8 MB
    _Float16* agl = (_Float16*)p;       p += (size_t)N_NODES * KP * 2;   // 12.8 MB
    _Float16* wch = (_Float16*)p;       p += (size_t)16 * WSTEP * 2;     //  9.34 MB
    _Float16* wcl = (_Float16*)p;       p += (size_t)16 * WSTEP * 2;     //  9.34 MB
    _Float16* wh_hi = (_Float16*)p;     p += (size_t)2 * WSTEP * 2;      //  1.17 MB
    _Float16* wh_lo = (_Float16*)p;     p += (size_t)2 * WSTEP * 2;      //  1.17 MB
    float* pooled = (float*)p;          p += 1216;
    int* row_ptr = (int*)p;             p += 80016;
    int* colx = (int*)p;                p += (size_t)N_EDGES * 4;        //  1.28 MB
    int* deg = (int*)p;                 p += 80000;
    int* cursor = (int*)p;              p += 80000;

    hipMemsetAsync(deg, 0, N_NODES * sizeof(int), stream);
    hipMemsetAsync(agh, 0, (size_t)N_NODES * KP * 2, stream);
    hipMemsetAsync(agl, 0, (size_t)N_NODES * KP * 2, stream);
    hipMemsetAsync(hh1, 0, (size_t)N_NODES * KP * 2, stream);
    hipMemsetAsync(hl1, 0, (size_t)N_NODES * KP * 2, stream);
    hipMemsetAsync(wch, 0, (size_t)16 * WSTEP * 2, stream);
    hipMemsetAsync(wcl, 0, (size_t)16 * WSTEP * 2, stream);
    hipMemsetAsync(wh_hi, 0, (size_t)2 * WSTEP * 2, stream);
    hipMemsetAsync(wh_lo, 0, (size_t)2 * WSTEP * 2, stream);
    hipMemsetAsync(pooled, 0, C * sizeof(float), stream);

    pad_kernel<<<(N_NODES * KP + 255) / 256, 256, 0, stream>>>(x, h, hh0, hl0);

    hist_kernel<<<(N_EDGES + 255) / 256, 256, 0, stream>>>(dst, deg);
    scan_kernel<<<1, 1024, 0, stream>>>(deg, row_ptr);
    cursor_copy<<<(N_NODES + 255) / 256, 256, 0, stream>>>(row_ptr, cursor);
    fill_kernel<<<(N_EDGES + 255) / 256, 256, 0, stream>>>(src, dst, cursor, colx);

    wcomb_split<<<dim3(15, 5, 16), 256, 0, stream>>>(W1, W2, g1_wih, g2_wih, wch, wcl);
    whh_split<<<(2 * 3 * C * C + 255) / 256, 256, 0, stream>>>(g1_whh, g2_whh, wh_hi, wh_lo);

    _Float16* hhr = hh0; _Float16* hlr = hl0;   // state to read
    _Float16* hhw = hh1; _Float16* hlw = hl1;   // state to write

    for (int layer = 0; layer < 2; ++layer) {
        const float* bih = layer ? g2_bih : g1_bih;
        const float* bhh = layer ? g2_bhh : g1_bhh;
        const _Float16* whh_hi = wh_hi + (size_t)layer * WSTEP;
        const _Float16* whh_lo = wh_lo + (size_t)layer * WSTEP;
        for (int step = 0; step < L_STEPS; ++step) {
            const _Float16* wc_hi = wch + (size_t)(layer * 8 + step) * WSTEP;
            const _Float16* wc_lo = wcl + (size_t)(layer * 8 + step) * WSTEP;
            aggregate_kernel<<<N_NODES / 4, 256, 0, stream>>>(h, row_ptr, colx, agh, agl);
            gru_f16<<<N_NODES / 32, 256, 0, stream>>>(
                hhr, hlr, hhw, hlw, agh, agl, wc_hi, wc_lo, whh_hi, whh_lo, bih, bhh, h);
            _Float16* t;
            t = hhr; hhr = hhw; hhw = t;
            t = hlr; hlr = hlw; hlw = t;
        }
        if (layer == 0)
            relu_kernel<<<(N_NODES * C + 255) / 256, 256, 0, stream>>>(h, hhr, hlr);
    }

    pool_kernel<<<256, 320, 0, stream>>>(h, pooled);
    lsm_kernel<<<1, 512, 0, stream>>>(pooled, (float*)d_out);
}